// Round 1
// baseline (278.223 us; speedup 1.0000x reference)
//
#include <hip/hip_runtime.h>

// ISDLoss_only_type1: masked symmetric KL between mixed conf and interpolation.
// B=128, N=8732, C=21; fp32 in, scalar fp32 out.

#define EPS 1e-7f

constexpr int B = 128;
constexpr int N = 8732;
constexpr int C = 21;
constexpr int ROWS = B * N;          // 1,117,696
constexpr int GRID = 1024;
constexpr int BLOCK = 256;

__global__ __launch_bounds__(BLOCK) void isd_main_kernel(
    const float* __restrict__ lam_p,
    const float* __restrict__ conf,
    const float* __restrict__ csh,   // conf_shuffle
    const float* __restrict__ cin,   // conf_interpolation
    double* __restrict__ partials)   // [2*GRID]: (sum, cnt) per block
{
    const float lam = lam_p[0];
    const float oml = 1.0f - lam;

    float sum = 0.0f;
    float cnt = 0.0f;

    const int stride = gridDim.x * blockDim.x;
    for (int r = blockIdx.x * blockDim.x + threadIdx.x; r < ROWS; r += stride) {
        const int b  = r / N;
        const int n  = r - b * N;
        const int b2 = b ^ (B / 2);              // (b + 64) % 128

        const float* pc = conf + (size_t)r * C;
        const float* pt = csh  + ((size_t)b2 * N + n) * C;
        const float* pi = cin  + (size_t)r * C;

        float c0 = 0.0f, t0 = 0.0f;
        float cmax = -1e30f, tmax = -1e30f;
        float kl = 0.0f;

        #pragma unroll
        for (int c = 0; c < C; ++c) {
            const float cv = pc[c];
            const float tv = pt[c];
            const float iv = pi[c] + EPS;
            const float mv = fmaf(lam, cv, oml * tv) + EPS;   // lam*conf + (1-lam)*conf_temp + eps
            const float lm = __logf(mv);
            const float li = __logf(iv);
            // kl_a + kl_b contribution per class:
            //   iv*(li-lm) + mv*(lm-li) == (iv - mv) * (li - lm)
            kl += (iv - mv) * (li - lm);
            if (c == 0) { c0 = cv; t0 = tv; }
            else        { cmax = fmaxf(cmax, cv); tmax = fmaxf(tmax, tv); }
        }

        const float msk = ((cmax > c0) && (tmax > t0)) ? 1.0f : 0.0f;
        sum += kl * msk;
        cnt += msk;
    }

    // wave (64-lane) shuffle reduction
    #pragma unroll
    for (int off = 32; off > 0; off >>= 1) {
        sum += __shfl_down(sum, off, 64);
        cnt += __shfl_down(cnt, off, 64);
    }

    __shared__ float s_sum[BLOCK / 64];
    __shared__ float s_cnt[BLOCK / 64];
    const int wave = threadIdx.x >> 6;
    const int lane = threadIdx.x & 63;
    if (lane == 0) { s_sum[wave] = sum; s_cnt[wave] = cnt; }
    __syncthreads();

    if (threadIdx.x == 0) {
        double bs = 0.0, bc = 0.0;
        #pragma unroll
        for (int w = 0; w < BLOCK / 64; ++w) { bs += (double)s_sum[w]; bc += (double)s_cnt[w]; }
        partials[2 * blockIdx.x + 0] = bs;
        partials[2 * blockIdx.x + 1] = bc;
    }
}

__global__ __launch_bounds__(64) void isd_final_kernel(
    const double* __restrict__ partials,
    float* __restrict__ out)
{
    double s = 0.0, c = 0.0;
    for (int i = threadIdx.x; i < GRID; i += 64) {
        s += partials[2 * i + 0];
        c += partials[2 * i + 1];
    }
    #pragma unroll
    for (int off = 32; off > 0; off >>= 1) {
        s += __shfl_down(s, off, 64);
        c += __shfl_down(c, off, 64);
    }
    if (threadIdx.x == 0) {
        float loss = 0.0f;
        if (c > 0.0) loss = (float)(s / fmax(c, 1.0) * 0.5);
        out[0] = loss;
    }
}

extern "C" void kernel_launch(void* const* d_in, const int* in_sizes, int n_in,
                              void* d_out, int out_size, void* d_ws, size_t ws_size,
                              hipStream_t stream) {
    const float* lam  = (const float*)d_in[0];
    const float* conf = (const float*)d_in[1];
    const float* csh  = (const float*)d_in[2];
    const float* cin  = (const float*)d_in[3];
    float* out = (float*)d_out;
    double* partials = (double*)d_ws;   // 2*GRID doubles = 16 KB

    isd_main_kernel<<<GRID, BLOCK, 0, stream>>>(lam, conf, csh, cin, partials);
    isd_final_kernel<<<1, 64, 0, stream>>>(partials, out);
}

// Round 2
// 274.656 us; speedup vs baseline: 1.0130x; 1.0130x over previous
//
#include <hip/hip_runtime.h>

// ISDLoss_only_type1: masked symmetric KL between mixed conf and interpolation.
// B=128, N=8732, C=21; fp32 in, scalar fp32 out.
//
// R2: LDS-staged tiles with coalesced float4 global loads (R1 was
// latency-bound on stride-84 scalar loads: 1.68 TB/s, VALUBusy 18%).

#define EPS 1e-7f

constexpr int B = 128;
constexpr int N = 8732;
constexpr int C = 21;
constexpr int ROWS = B * N;               // 1,117,696 = 256 * 4366 exactly
constexpr int TILE = 256;                 // rows per block
constexpr int BLOCK = 256;
constexpr int GRID = ROWS / TILE;         // 4366
constexpr int TILE_ELEMS = TILE * C;      // 5376 floats (21504 B, 16B-aligned)
constexpr int TILE_F4 = TILE_ELEMS / 4;   // 1344
constexpr int BATCH_F4 = (N * C) / 4;     // 45843 (N*C=183372, %4==0 -> no straddle)

__global__ __launch_bounds__(BLOCK) void isd_main_kernel(
    const float* __restrict__ lam_p,
    const float* __restrict__ conf,
    const float* __restrict__ csh,   // conf_shuffle
    const float* __restrict__ cin,   // conf_interpolation
    double* __restrict__ partials)   // [2*GRID]: (sum, cnt) per block
{
    __shared__ float s_conf[TILE_ELEMS];
    __shared__ float s_csh [TILE_ELEMS];
    __shared__ float s_cin [TILE_ELEMS];

    const int tid = threadIdx.x;
    const int tileF4base = blockIdx.x * TILE_F4;

    const float4* conf4 = (const float4*)conf;
    const float4* csh4  = (const float4*)csh;
    const float4* cin4  = (const float4*)cin;

    // ---- stage: fully coalesced float4 loads ----
    for (int k = tid; k < TILE_F4; k += BLOCK) {
        const int G = tileF4base + k;
        ((float4*)s_conf)[k] = conf4[G];
        ((float4*)s_cin )[k] = cin4[G];
        // batch-half swap for conf_shuffle; float4 never straddles a batch
        const int b  = G / BATCH_F4;
        const int G2 = G + ((b ^ 64) - b) * BATCH_F4;
        ((float4*)s_csh)[k] = csh4[G2];
    }
    __syncthreads();

    const float lam = lam_p[0];
    const float oml = 1.0f - lam;

    // ---- compute: one thread per row; stride-21 LDS reads = 2 lanes/bank (free) ----
    const float* pc = s_conf + tid * C;
    const float* pt = s_csh  + tid * C;
    const float* pi = s_cin  + tid * C;

    float c0 = 0.0f, t0 = 0.0f;
    float cmax = -1e30f, tmax = -1e30f;
    float kl = 0.0f;

    #pragma unroll
    for (int c = 0; c < C; ++c) {
        const float cv = pc[c];
        const float tv = pt[c];
        const float iv = pi[c] + EPS;
        const float mv = fmaf(lam, cv, oml * tv) + EPS;
        // kl_a + kl_b per class: iv*(li-lm) + mv*(lm-li) == (iv-mv)*(li-lm)
        kl += (iv - mv) * (__logf(iv) - __logf(mv));
        if (c == 0) { c0 = cv; t0 = tv; }
        else        { cmax = fmaxf(cmax, cv); tmax = fmaxf(tmax, tv); }
    }

    const float msk = ((cmax > c0) && (tmax > t0)) ? 1.0f : 0.0f;
    float sum = kl * msk;
    float cnt = msk;

    // ---- reduce: wave shuffle -> LDS -> per-block double partial ----
    #pragma unroll
    for (int off = 32; off > 0; off >>= 1) {
        sum += __shfl_down(sum, off, 64);
        cnt += __shfl_down(cnt, off, 64);
    }

    __shared__ float r_sum[BLOCK / 64];
    __shared__ float r_cnt[BLOCK / 64];
    const int wave = tid >> 6;
    const int lane = tid & 63;
    if (lane == 0) { r_sum[wave] = sum; r_cnt[wave] = cnt; }
    __syncthreads();

    if (tid == 0) {
        double bs = 0.0, bc = 0.0;
        #pragma unroll
        for (int w = 0; w < BLOCK / 64; ++w) { bs += (double)r_sum[w]; bc += (double)r_cnt[w]; }
        partials[2 * blockIdx.x + 0] = bs;
        partials[2 * blockIdx.x + 1] = bc;
    }
}

__global__ __launch_bounds__(256) void isd_final_kernel(
    const double* __restrict__ partials,
    float* __restrict__ out)
{
    double s = 0.0, c = 0.0;
    for (int i = threadIdx.x; i < GRID; i += 256) {
        s += partials[2 * i + 0];
        c += partials[2 * i + 1];
    }
    #pragma unroll
    for (int off = 32; off > 0; off >>= 1) {
        s += __shfl_down(s, off, 64);
        c += __shfl_down(c, off, 64);
    }
    __shared__ double ss[4], sc[4];
    const int wave = threadIdx.x >> 6;
    const int lane = threadIdx.x & 63;
    if (lane == 0) { ss[wave] = s; sc[wave] = c; }
    __syncthreads();
    if (threadIdx.x == 0) {
        const double S  = ss[0] + ss[1] + ss[2] + ss[3];
        const double Cc = sc[0] + sc[1] + sc[2] + sc[3];
        out[0] = (Cc > 0.0) ? (float)(S / fmax(Cc, 1.0) * 0.5) : 0.0f;
    }
}

extern "C" void kernel_launch(void* const* d_in, const int* in_sizes, int n_in,
                              void* d_out, int out_size, void* d_ws, size_t ws_size,
                              hipStream_t stream) {
    const float* lam  = (const float*)d_in[0];
    const float* conf = (const float*)d_in[1];
    const float* csh  = (const float*)d_in[2];
    const float* cin  = (const float*)d_in[3];
    float* out = (float*)d_out;
    double* partials = (double*)d_ws;   // 2*GRID doubles = ~70 KB

    isd_main_kernel<<<GRID, BLOCK, 0, stream>>>(lam, conf, csh, cin, partials);
    isd_final_kernel<<<1, 256, 0, stream>>>(partials, out);
}